// Round 15
// baseline (2232.292 us; speedup 1.0000x reference)
//
#include <hip/hip_runtime.h>
#include <hip/hip_bf16.h>
#include <math.h>

#define B 8
#define L 197
#define DM 192
#define DI 384
#define NS 16
#define RK 12
#define DEPTH_ 24
#define MROWS (B*L)   // 1576
#define XDN 416       // x_dbl row: 384 dt (softplus'd) + 16 B + 16 C

typedef __bf16 bf16x8 __attribute__((ext_vector_type(8)));
typedef __bf16 bf16x4 __attribute__((ext_vector_type(4)));
typedef float  f32x4  __attribute__((ext_vector_type(4)));

#define MFMA __builtin_amdgcn_mfma_f32_16x16x32_bf16

__device__ __forceinline__ float siluf(float x) { return x / (1.f + __expf(-x)); }

// DPP-based 16-lane row reduction (VALU-rate, no LDS pipe).
template<int CTRL>
__device__ __forceinline__ float dpp_addf(float s) {
    int v = __builtin_amdgcn_mov_dpp(__builtin_bit_cast(int, s), CTRL, 0xF, 0xF, true);
    return s + __builtin_bit_cast(float, v);
}
__device__ __forceinline__ float row_sum16(float p) {
    p = dpp_addf<0xB1>(p);    // quad_perm xor1
    p = dpp_addf<0x4E>(p);    // quad_perm xor2
    p = dpp_addf<0x141>(p);   // row_half_mirror
    p = dpp_addf<0x140>(p);   // row_mirror
    return p;
}

// ===========================================================================
// Init kernels (once, off critical path).
// ===========================================================================
__global__ __launch_bounds__(384)
void waug_k(const float* __restrict__ xw, const float* __restrict__ dtw,
            __bf16* __restrict__ waug)
{
    int l = blockIdx.y, n = blockIdx.x, k = threadIdx.x;
    const float* xwl = xw + (size_t)l * 44 * DI;
    float v;
    if (n < 384) {
        const float* dr = dtw + ((size_t)l * DI + n) * RK;
        float a = 0.f;
        #pragma unroll
        for (int r = 0; r < RK; ++r) a += dr[r] * xwl[r * DI + k];
        v = a;
    } else if (n < 400) {
        v = xwl[(12 + n - 384) * DI + k];
    } else {
        v = xwl[(28 + n - 400) * DI + k];
    }
    waug[((size_t)l * XDN + n) * DI + k] = (__bf16)v;
}

__global__ __launch_bounds__(256)
void f2bf_k(const float* __restrict__ src, __bf16* __restrict__ dst, int n)
{
    int i = blockIdx.x * 256 + threadIdx.x;
    if (i < n) dst[i] = (__bf16)src[i];
}

// ===========================================================================
// MFMA tile geometry: frag row=lane&15, k=(lane>>4)*8; D: col=lane&15,
// row=(lane>>4)*4+reg  [m89-verified mapping].
// ===========================================================================

// ---------------------------------------------------------------------------
// Patch embed as GEMM: [1568,768] @ patch_w[192,768]^T. BM=32, grid (3,49).
// ---------------------------------------------------------------------------
__global__ __launch_bounds__(256)
void patch_gemm_k(const float* __restrict__ x, const float* __restrict__ pw,
                  const float* __restrict__ pb, const float* __restrict__ pos,
                  float* __restrict__ residual)
{
    __shared__ __bf16 Xs[32][136];
    __shared__ __bf16 Ws[64][136];
    const int bm = blockIdx.y * 32;
    const int bn = blockIdx.x * 64;
    const int tid = threadIdx.x;
    const int lane = tid & 63, wv = tid >> 6;
    const int wm = (wv >> 1) * 16, wn = (wv & 1) * 32;
    const int lr = lane & 15, lk = (lane >> 4) * 8;
    f32x4 acc[2] = {};
    for (int k0 = 0; k0 < 768; k0 += 128) {
        for (int i = tid; i < 32 * 32; i += 256) {
            int r = i >> 5, k4 = (i & 31) * 4;
            int gm = bm + r;
            int b = gm / 196, f = gm % 196;
            int py = f / 14, px = f % 14;
            int k = k0 + k4;
            int ci = k >> 8, rem = k & 255, ky = rem >> 4, kx = rem & 15;
            float4 v = *(const float4*)&x[(((size_t)b * 3 + ci) * 224 + py * 16 + ky) * 224 + px * 16 + kx];
            Xs[r][k4+0] = (__bf16)v.x; Xs[r][k4+1] = (__bf16)v.y;
            Xs[r][k4+2] = (__bf16)v.z; Xs[r][k4+3] = (__bf16)v.w;
        }
        for (int i = tid; i < 64 * 32; i += 256) {
            int r = i >> 5, k4 = (i & 31) * 4;
            float4 v = *(const float4*)&pw[(size_t)(bn + r) * 768 + k0 + k4];
            Ws[r][k4+0] = (__bf16)v.x; Ws[r][k4+1] = (__bf16)v.y;
            Ws[r][k4+2] = (__bf16)v.z; Ws[r][k4+3] = (__bf16)v.w;
        }
        __syncthreads();
        #pragma unroll
        for (int ks = 0; ks < 128; ks += 32) {
            bf16x8 a0 = *(const bf16x8*)&Xs[wm + lr][ks + lk];
            bf16x8 b0 = *(const bf16x8*)&Ws[wn + lr][ks + lk];
            bf16x8 b1 = *(const bf16x8*)&Ws[wn + 16 + lr][ks + lk];
            acc[0] = MFMA(a0, b0, acc[0], 0, 0, 0);
            acc[1] = MFMA(a0, b1, acc[1], 0, 0, 0);
        }
        __syncthreads();
    }
    #pragma unroll
    for (int q = 0; q < 4; ++q) {
        int gm = bm + wm + (lane >> 4) * 4 + q;
        int b = gm / 196, f = gm % 196;
        int p = f + (f >= 98);
        #pragma unroll
        for (int j = 0; j < 2; ++j) {
            int gn = bn + wn + j * 16 + (lane & 15);
            residual[((size_t)b * L + p) * DM + gn] =
                acc[j][q] + pb[gn] + pos[(size_t)p * DM + gn];
        }
    }
}

__global__ __launch_bounds__(192)
void cls_pos_k(const float* __restrict__ cls, const float* __restrict__ pos,
               float* __restrict__ residual)
{
    int c = threadIdx.x;
    float v = cls[c] + pos[98 * DM + c];
    for (int b = 0; b < B; ++b)
        residual[((size_t)b * L + 98) * DM + c] = v;
}

// ---------------------------------------------------------------------------
// FUSED gemm1 + conv: xz = rmsnorm(residual)*nw @ w1bf^T   [1576,192]x[768,192]^T
// BN=96 -> grid (8,25). xi-half blocks (bn<384) keep their xz tile in LDS,
// recompute the 3 boundary rows (scalar dot), run depthwise conv+silu in-LDS
// and write xcb16 directly (xi half never hits global). z-half blocks write
// the gate to compact zb16.
// LDS: Xs 25.6K + Ws 38.4K = 64000 B; cs[67][104] (13.9K) aliases Xs post-MFMA.
// ---------------------------------------------------------------------------
__global__ __launch_bounds__(256)
void gemm1_conv_k(const float* __restrict__ residual, const float* __restrict__ nw,
                  const __bf16* __restrict__ w1bf, const float* __restrict__ cw,
                  const float* __restrict__ cb, __bf16* __restrict__ zb16,
                  __bf16* __restrict__ xcb16)
{
    __shared__ __align__(16) char smem[64000];
    __shared__ float sinv[64];
    __shared__ float sinvB[3];
    auto Xs = (__bf16 (*)[200])smem;
    auto Ws = (__bf16 (*)[200])(smem + 25600);
    auto cs = (__bf16 (*)[104])smem;   // aliases Xs region after MFMA

    const int bm = blockIdx.y * 64;
    const int bn = blockIdx.x * 96;
    const int tid = threadIdx.x;
    const int lane = tid & 63, wv = tid >> 6;
    const int wm = (wv >> 1) * 32, wn = (wv & 1) * 48;
    const int lr = lane & 15, lk = (lane >> 4) * 8;

    {   // per-row inv rms: 4 threads/row
        int r = tid >> 2, q = tid & 3;
        int gm = bm + r;
        float s = 0.f;
        if (gm < MROWS) {
            const float4* xr = (const float4*)(residual + (size_t)gm * DM);
            #pragma unroll
            for (int i = 0; i < 12; ++i) {
                float4 v = xr[q + i * 4];
                s += v.x*v.x + v.y*v.y + v.z*v.z + v.w*v.w;
            }
        }
        s += __shfl_xor(s, 1, 4);
        s += __shfl_xor(s, 2, 4);
        if (q == 0) sinv[r] = rsqrtf(s * (1.f / DM) + 1e-5f);
    }
    __syncthreads();
    for (int i = tid; i < 64 * 48; i += 256) {
        int r = i / 48, k4 = (i % 48) * 4;
        int gm = bm + r;
        float4 v = {0.f, 0.f, 0.f, 0.f};
        if (gm < MROWS) v = *(const float4*)&residual[(size_t)gm * DM + k4];
        float sc = sinv[r];
        float4 w4 = *(const float4*)&nw[k4];
        Xs[r][k4+0] = (__bf16)(v.x * sc * w4.x);
        Xs[r][k4+1] = (__bf16)(v.y * sc * w4.y);
        Xs[r][k4+2] = (__bf16)(v.z * sc * w4.z);
        Xs[r][k4+3] = (__bf16)(v.w * sc * w4.w);
    }
    for (int i = tid; i < 96 * 24; i += 256) {
        int r = i / 24, c8 = (i % 24) * 8;
        *(bf16x8*)&Ws[r][c8] = *(const bf16x8*)&w1bf[(size_t)(bn + r) * DM + c8];
    }
    __syncthreads();
    f32x4 acc[2][3] = {};
    #pragma unroll
    for (int ks = 0; ks < 192; ks += 32) {
        bf16x8 a0 = *(const bf16x8*)&Xs[wm + lr][ks + lk];
        bf16x8 a1 = *(const bf16x8*)&Xs[wm + 16 + lr][ks + lk];
        #pragma unroll
        for (int n = 0; n < 3; ++n) {
            bf16x8 bb = *(const bf16x8*)&Ws[wn + n * 16 + lr][ks + lk];
            acc[0][n] = MFMA(a0, bb, acc[0][n], 0, 0, 0);
            acc[1][n] = MFMA(a1, bb, acc[1][n], 0, 0, 0);
        }
    }

    if (bn >= 384) {
        // z half: write gate directly (compact layout [MROWS][DI])
        #pragma unroll
        for (int i = 0; i < 2; ++i)
            #pragma unroll
            for (int q = 0; q < 4; ++q) {
                int gm = bm + wm + i * 16 + (lane >> 4) * 4 + q;
                if (gm >= MROWS) continue;
                #pragma unroll
                for (int n = 0; n < 3; ++n) {
                    int gz = bn - 384 + wn + n * 16 + (lane & 15);
                    zb16[(size_t)gm * DI + gz] = (__bf16)acc[i][n][q];
                }
            }
        return;
    }

    // xi half: conv path. Overwrite Xs region with the xz tile (+3 boundary rows).
    __syncthreads();            // everyone done reading Xs/Ws
    #pragma unroll
    for (int i = 0; i < 2; ++i)
        #pragma unroll
        for (int q = 0; q < 4; ++q) {
            int lrow = wm + i * 16 + (lane >> 4) * 4 + q;
            #pragma unroll
            for (int n = 0; n < 3; ++n)
                cs[3 + lrow][wn + n * 16 + (lane & 15)] = (__bf16)acc[i][n][q];
        }
    if (tid < 3) {              // boundary row rms
        int br = bm - 3 + tid;
        float s = 0.f;
        if (br >= 0) {
            const float* rr = residual + (size_t)br * DM;
            for (int k = 0; k < DM; ++k) s += rr[k] * rr[k];
        }
        sinvB[tid] = rsqrtf(s * (1.f / DM) + 1e-5f);
    }
    __syncthreads();
    for (int o = tid; o < 3 * 96; o += 256) {     // boundary rows: scalar dot
        int jj = o / 96, c = o % 96;
        int br = bm - 3 + jj;
        float a = 0.f;
        if (br >= 0) {
            float sc = sinvB[jj];
            const float* rr = residual + (size_t)br * DM;
            const __bf16* wr = w1bf + (size_t)(bn + c) * DM;
            #pragma unroll 8
            for (int k = 0; k < DM; ++k)
                a += (float)(__bf16)(rr[k] * sc * nw[k]) * (float)wr[k];
        }
        cs[jj][c] = (__bf16)a;
    }
    __syncthreads();
    for (int o = tid; o < 64 * 96; o += 256) {    // conv + silu -> xcb16
        int r = o / 96, c = o % 96;
        int gm = bm + r;
        if (gm >= MROWS) continue;
        int d = bn + c;
        int t = gm % L;
        float a = cb[d];
        #pragma unroll
        for (int j = 0; j < 4; ++j)
            if (t - 3 + j >= 0) a += (float)cs[r + j][c] * cw[d * 4 + j];
        xcb16[(size_t)gm * DI + d] = (__bf16)siluf(a);
    }
}

// ---------------------------------------------------------------------------
// gemm2: xdb = xc_bf16 @ W_aug^T  [1576,384]x[416,384]^T, grid (7,25)=175.
// Softplus + dt bias epilogue on first 384 output channels.
// ---------------------------------------------------------------------------
__global__ __launch_bounds__(256)
void gemm2_k(const __bf16* __restrict__ xcb16, const __bf16* __restrict__ waug,
             const float* __restrict__ dtbias, float* __restrict__ xdb)
{
    __shared__ __bf16 Xs[64][136];
    __shared__ __bf16 Ws[64][136];
    const int bm = blockIdx.y * 64;
    const int bn = blockIdx.x * 64;
    const int tid = threadIdx.x;
    const int lane = tid & 63, wv = tid >> 6;
    const int wm = (wv >> 1) * 32, wn = (wv & 1) * 32;
    const int lr = lane & 15, lk = (lane >> 4) * 8;
    f32x4 acc[2][2] = {};
    for (int k0 = 0; k0 < DI; k0 += 128) {
        for (int i = tid; i < 64 * 16; i += 256) {
            int r = i >> 4, c8 = (i & 15) * 8;
            int gm = bm + r;
            bf16x8 v = {};
            if (gm < MROWS) v = *(const bf16x8*)&xcb16[(size_t)gm * DI + k0 + c8];
            *(bf16x8*)&Xs[r][c8] = v;
        }
        for (int i = tid; i < 64 * 16; i += 256) {
            int r = i >> 4, c8 = (i & 15) * 8;
            int gn = bn + r;
            bf16x8 v = {};
            if (gn < XDN) v = *(const bf16x8*)&waug[(size_t)gn * DI + k0 + c8];
            *(bf16x8*)&Ws[r][c8] = v;
        }
        __syncthreads();
        #pragma unroll
        for (int ks = 0; ks < 128; ks += 32) {
            bf16x8 a0 = *(const bf16x8*)&Xs[wm + lr][ks + lk];
            bf16x8 a1 = *(const bf16x8*)&Xs[wm + 16 + lr][ks + lk];
            bf16x8 b0 = *(const bf16x8*)&Ws[wn + lr][ks + lk];
            bf16x8 b1 = *(const bf16x8*)&Ws[wn + 16 + lr][ks + lk];
            acc[0][0] = MFMA(a0, b0, acc[0][0], 0, 0, 0);
            acc[0][1] = MFMA(a0, b1, acc[0][1], 0, 0, 0);
            acc[1][0] = MFMA(a1, b0, acc[1][0], 0, 0, 0);
            acc[1][1] = MFMA(a1, b1, acc[1][1], 0, 0, 0);
        }
        __syncthreads();
    }
    #pragma unroll
    for (int i = 0; i < 2; ++i)
        #pragma unroll
        for (int q = 0; q < 4; ++q) {
            int gm = bm + wm + i * 16 + (lane >> 4) * 4 + q;
            if (gm >= MROWS) continue;
            #pragma unroll
            for (int j = 0; j < 2; ++j) {
                int gn = bn + wn + j * 16 + (lane & 15);
                if (gn >= XDN) continue;
                float v = acc[i][j][q];
                if (gn < 384) {
                    v += dtbias[gn];
                    v = (v > 20.f) ? v : __logf(1.f + __expf(v));
                }
                xdb[(size_t)gm * XDN + gn] = v;
            }
        }
}

// ---------------------------------------------------------------------------
// Selective scan. Staging: dt/B/C coalesced fp32 from xdb; u from bf16 xcb16;
// z (gate) from compact bf16 zb16. DPP reduce + fast exp. Output bf16. grid 192.
// ---------------------------------------------------------------------------
__global__ __launch_bounds__(256)
void scan_fused_k(const float* __restrict__ xdb, const __bf16* __restrict__ xcb16,
                  const __bf16* __restrict__ zb16, const float* __restrict__ Alog,
                  const float* __restrict__ Dp, __bf16* __restrict__ yg16)
{
    __shared__ float sdt[L * 16];
    __shared__ float su [L * 16];
    __shared__ float sB [L * 16];
    __shared__ float sC [L * 16];
    __shared__ float sy [L * 16];

    const int blk = blockIdx.x;
    const int b = blk / (DI / 16);
    const int dc = blk % (DI / 16);
    const int tid = threadIdx.x;

    for (int idx = tid; idx < L * 16; idx += 256) {
        int t = idx >> 4, c = idx & 15;
        size_t row = (size_t)(b * L + t);
        const float* xr = xdb + row * XDN;
        sdt[idx] = xr[dc * 16 + c];
        sB[idx]  = xr[384 + c];
        sC[idx]  = xr[400 + c];
        su[idx]  = (float)xcb16[row * DI + dc * 16 + c];
    }
    __syncthreads();

    const int nl = tid & 15;
    const int dl = tid >> 4;
    const int d = dc * 16 + dl;
    const float Acoef = -__expf(Alog[d * NS + nl]);
    const float Dv = Dp[d];
    float h = 0.f;
    #pragma unroll 8
    for (int t = 0; t < L; ++t) {
        float dtv = sdt[t * 16 + dl];
        float u   = su [t * 16 + dl];
        float Bv  = sB [t * 16 + nl];
        float Cv  = sC [t * 16 + nl];
        float dA = __expf(dtv * Acoef);
        h = dA * h + (dtv * u) * Bv;
        float p = row_sum16(h * Cv);
        if (nl == 0) sy[t * 16 + dl] = p + u * Dv;
    }
    __syncthreads();

    for (int idx = tid; idx < L * 16; idx += 256) {
        int t = idx >> 4, c = idx & 15;
        size_t row = (size_t)(b * L + t);
        float z = (float)zb16[row * DI + dc * 16 + c];
        yg16[row * DI + dc * 16 + c] = (__bf16)(sy[idx] * siluf(z));
    }
}

// ---------------------------------------------------------------------------
// gemm3: residual += yg16 @ w3bf^T  [1576,384]x[192,384]^T. grid (3, 25).
// Both operands staged from bf16.
// ---------------------------------------------------------------------------
__global__ __launch_bounds__(256)
void gemm3_resid_k(const __bf16* __restrict__ yg16, const __bf16* __restrict__ w3bf,
                   float* __restrict__ residual)
{
    __shared__ __bf16 Xs[64][136];
    __shared__ __bf16 Ws[64][136];
    const int bm = blockIdx.y * 64;
    const int bn = blockIdx.x * 64;
    const int tid = threadIdx.x;
    const int lane = tid & 63, wv = tid >> 6;
    const int wm = (wv >> 1) * 32, wn = (wv & 1) * 32;
    const int lr = lane & 15, lk = (lane >> 4) * 8;
    f32x4 acc[2][2] = {};
    for (int k0 = 0; k0 < DI; k0 += 128) {
        for (int i = tid; i < 64 * 16; i += 256) {
            int r = i >> 4, c8 = (i & 15) * 8;
            int gm = bm + r;
            bf16x8 v = {};
            if (gm < MROWS) v = *(const bf16x8*)&yg16[(size_t)gm * DI + k0 + c8];
            *(bf16x8*)&Xs[r][c8] = v;
        }
        for (int i = tid; i < 64 * 16; i += 256) {
            int r = i >> 4, c8 = (i & 15) * 8;
            *(bf16x8*)&Ws[r][c8] = *(const bf16x8*)&w3bf[(size_t)(bn + r) * DI + k0 + c8];
        }
        __syncthreads();
        #pragma unroll
        for (int ks = 0; ks < 128; ks += 32) {
            bf16x8 a0 = *(const bf16x8*)&Xs[wm + lr][ks + lk];
            bf16x8 a1 = *(const bf16x8*)&Xs[wm + 16 + lr][ks + lk];
            bf16x8 b0 = *(const bf16x8*)&Ws[wn + lr][ks + lk];
            bf16x8 b1 = *(const bf16x8*)&Ws[wn + 16 + lr][ks + lk];
            acc[0][0] = MFMA(a0, b0, acc[0][0], 0, 0, 0);
            acc[0][1] = MFMA(a0, b1, acc[0][1], 0, 0, 0);
            acc[1][0] = MFMA(a1, b0, acc[1][0], 0, 0, 0);
            acc[1][1] = MFMA(a1, b1, acc[1][1], 0, 0, 0);
        }
        __syncthreads();
    }
    #pragma unroll
    for (int i = 0; i < 2; ++i)
        #pragma unroll
        for (int q = 0; q < 4; ++q) {
            int gm = bm + wm + i * 16 + (lane >> 4) * 4 + q;
            if (gm >= MROWS) continue;
            #pragma unroll
            for (int j = 0; j < 2; ++j) {
                int gn = bn + wn + j * 16 + (lane & 15);
                size_t off = (size_t)gm * DM + gn;
                residual[off] += acc[i][j][q];
            }
        }
}

// ---------------------------------------------------------------------------
// Final: rmsnorm(residual) at cls row then head GEMV. One block/batch.
// ---------------------------------------------------------------------------
__global__ __launch_bounds__(256)
void final_head_k(const float* __restrict__ residual, const float* __restrict__ nfw,
                  const float* __restrict__ hw, const float* __restrict__ hb,
                  float* __restrict__ out)
{
    int b = blockIdx.x;
    int tid = threadIdx.x;
    __shared__ float rowv[DM];
    __shared__ float wsum[4];
    size_t off = ((size_t)b * L + 98) * DM;
    float v = 0.f;
    if (tid < DM) v = residual[off + tid];
    float s = v * v;
    #pragma unroll
    for (int o = 32; o; o >>= 1) s += __shfl_down(s, o);
    if ((tid & 63) == 0) wsum[tid >> 6] = s;
    __syncthreads();
    float total = wsum[0] + wsum[1] + wsum[2] + wsum[3];
    float rs = rsqrtf(total * (1.f / DM) + 1e-5f);
    if (tid < DM) rowv[tid] = v * rs * nfw[tid];
    __syncthreads();
    for (int o = tid; o < 1000; o += 256) {
        float acc = hb[o];
        const float* w = hw + (size_t)o * DM;
        #pragma unroll 8
        for (int k = 0; k < DM; ++k) acc += w[k] * rowv[k];
        out[(size_t)b * 1000 + o] = acc;
    }
}

// ---------------------------------------------------------------------------
extern "C" void kernel_launch(void* const* d_in, const int* in_sizes, int n_in,
                              void* d_out, int out_size, void* d_ws, size_t ws_size,
                              hipStream_t stream)
{
    const float* x        = (const float*)d_in[0];
    const float* patch_w  = (const float*)d_in[1];
    const float* patch_b  = (const float*)d_in[2];
    const float* cls_tok  = (const float*)d_in[3];
    const float* pos_emb  = (const float*)d_in[4];
    const float* norm_w   = (const float*)d_in[5];
    const float* in_w     = (const float*)d_in[6];
    const float* conv_w   = (const float*)d_in[7];
    const float* conv_b   = (const float*)d_in[8];
    const float* xproj_w  = (const float*)d_in[9];
    const float* dt_w     = (const float*)d_in[10];
    const float* dt_b     = (const float*)d_in[11];
    const float* A_log    = (const float*)d_in[12];
    const float* D_par    = (const float*)d_in[13];
    const float* out_w    = (const float*)d_in[14];
    const float* norm_fw  = (const float*)d_in[15];
    const float* head_w   = (const float*)d_in[16];
    const float* head_b   = (const float*)d_in[17];

    float* ws = (float*)d_ws;
    float* residual = ws;  ws += (size_t)MROWS * DM;
    float* xdb      = ws;  ws += (size_t)MROWS * XDN;
    __bf16* zb16    = (__bf16*)ws;  ws += (size_t)MROWS * DI / 2;
    __bf16* xcb16   = (__bf16*)ws;  ws += (size_t)MROWS * DI / 2;
    __bf16* yg16    = (__bf16*)ws;  ws += (size_t)MROWS * DI / 2;
    __bf16* waug    = (__bf16*)ws;  ws += (size_t)DEPTH_ * XDN * DI / 2;
    __bf16* w1bf    = (__bf16*)ws;  ws += (size_t)DEPTH_ * 2 * DI * DM / 2;
    __bf16* w3bf    = (__bf16*)ws;  ws += (size_t)DEPTH_ * DM * DI / 2;

    const int n1 = DEPTH_ * 2 * DI * DM;
    const int n3 = DEPTH_ * DM * DI;
    waug_k<<<dim3(XDN, DEPTH_), 384, 0, stream>>>(xproj_w, dt_w, waug);
    f2bf_k<<<(n1 + 255) / 256, 256, 0, stream>>>(in_w, w1bf, n1);
    f2bf_k<<<(n3 + 255) / 256, 256, 0, stream>>>(out_w, w3bf, n3);
    patch_gemm_k<<<dim3(3, 49), 256, 0, stream>>>(x, patch_w, patch_b, pos_emb, residual);
    cls_pos_k<<<1, DM, 0, stream>>>(cls_tok, pos_emb, residual);

    for (int l = 0; l < DEPTH_; ++l) {
        gemm1_conv_k<<<dim3(8, 25), 256, 0, stream>>>(residual, norm_w + l * DM,
                                                      w1bf + (size_t)l * 2 * DI * DM,
                                                      conv_w + l * DI * 4, conv_b + l * DI,
                                                      zb16, xcb16);
        gemm2_k<<<dim3(7, 25), 256, 0, stream>>>(xcb16, waug + (size_t)l * XDN * DI,
                                                 dt_b + l * DI, xdb);
        scan_fused_k<<<B * (DI / 16), 256, 0, stream>>>(xdb, xcb16, zb16,
                                                        A_log + (size_t)l * DI * NS,
                                                        D_par + l * DI, yg16);
        gemm3_resid_k<<<dim3(3, 25), 256, 0, stream>>>(yg16, w3bf + (size_t)l * DM * DI,
                                                       residual);
    }
    final_head_k<<<B, 256, 0, stream>>>(residual, norm_fw, head_w, head_b, (float*)d_out);
}

// Round 16
// 1885.280 us; speedup vs baseline: 1.1841x; 1.1841x over previous
//
#include <hip/hip_runtime.h>
#include <hip/hip_bf16.h>
#include <math.h>

#define B 8
#define L 197
#define DM 192
#define DI 384
#define NS 16
#define RK 12
#define DEPTH_ 24
#define MROWS (B*L)   // 1576
#define XDN 416       // x_dbl row: 384 dt (softplus'd) + 16 B + 16 C

typedef __bf16 bf16x8 __attribute__((ext_vector_type(8)));
typedef __bf16 bf16x4 __attribute__((ext_vector_type(4)));
typedef float  f32x4  __attribute__((ext_vector_type(4)));

#define MFMA __builtin_amdgcn_mfma_f32_16x16x32_bf16

__device__ __forceinline__ float siluf(float x) { return x / (1.f + __expf(-x)); }

// DPP-based 16-lane row reduction (VALU-rate, no LDS pipe).
template<int CTRL>
__device__ __forceinline__ float dpp_addf(float s) {
    int v = __builtin_amdgcn_mov_dpp(__builtin_bit_cast(int, s), CTRL, 0xF, 0xF, true);
    return s + __builtin_bit_cast(float, v);
}
__device__ __forceinline__ float row_sum16(float p) {
    p = dpp_addf<0xB1>(p);    // quad_perm xor1
    p = dpp_addf<0x4E>(p);    // quad_perm xor2
    p = dpp_addf<0x141>(p);   // row_half_mirror
    p = dpp_addf<0x140>(p);   // row_mirror
    return p;
}

// ===========================================================================
// Init kernels (once, off critical path).
// ===========================================================================
__global__ __launch_bounds__(384)
void waug_k(const float* __restrict__ xw, const float* __restrict__ dtw,
            __bf16* __restrict__ waug)
{
    int l = blockIdx.y, n = blockIdx.x, k = threadIdx.x;
    const float* xwl = xw + (size_t)l * 44 * DI;
    float v;
    if (n < 384) {
        const float* dr = dtw + ((size_t)l * DI + n) * RK;
        float a = 0.f;
        #pragma unroll
        for (int r = 0; r < RK; ++r) a += dr[r] * xwl[r * DI + k];
        v = a;
    } else if (n < 400) {
        v = xwl[(12 + n - 384) * DI + k];
    } else {
        v = xwl[(28 + n - 400) * DI + k];
    }
    waug[((size_t)l * XDN + n) * DI + k] = (__bf16)v;
}

__global__ __launch_bounds__(256)
void f2bf_k(const float* __restrict__ src, __bf16* __restrict__ dst, int n)
{
    int i = blockIdx.x * 256 + threadIdx.x;
    if (i < n) dst[i] = (__bf16)src[i];
}

// ===========================================================================
// MFMA tile geometry: frag row=lane&15, k=(lane>>4)*8; D: col=lane&15,
// row=(lane>>4)*4+reg  [m89-verified mapping].
// ===========================================================================

// ---------------------------------------------------------------------------
// Patch embed as GEMM: [1568,768] @ patch_w[192,768]^T. BM=16, grid (3,98).
// ---------------------------------------------------------------------------
__global__ __launch_bounds__(256)
void patch_gemm_k(const float* __restrict__ x, const float* __restrict__ pw,
                  const float* __restrict__ pb, const float* __restrict__ pos,
                  float* __restrict__ residual)
{
    __shared__ __bf16 Xs[16][136];
    __shared__ __bf16 Ws[64][136];
    const int bm = blockIdx.y * 16;
    const int bn = blockIdx.x * 64;
    const int tid = threadIdx.x;
    const int lane = tid & 63, wv = tid >> 6;
    const int wn = wv * 16;
    const int lr = lane & 15, lk = (lane >> 4) * 8;
    f32x4 acc = {};
    for (int k0 = 0; k0 < 768; k0 += 128) {
        for (int i = tid; i < 16 * 32; i += 256) {
            int r = i >> 5, k4 = (i & 31) * 4;
            int gm = bm + r;
            int b = gm / 196, f = gm % 196;
            int py = f / 14, px = f % 14;
            int k = k0 + k4;
            int ci = k >> 8, rem = k & 255, ky = rem >> 4, kx = rem & 15;
            float4 v = *(const float4*)&x[(((size_t)b * 3 + ci) * 224 + py * 16 + ky) * 224 + px * 16 + kx];
            Xs[r][k4+0] = (__bf16)v.x; Xs[r][k4+1] = (__bf16)v.y;
            Xs[r][k4+2] = (__bf16)v.z; Xs[r][k4+3] = (__bf16)v.w;
        }
        for (int i = tid; i < 64 * 32; i += 256) {
            int r = i >> 5, k4 = (i & 31) * 4;
            float4 v = *(const float4*)&pw[(size_t)(bn + r) * 768 + k0 + k4];
            Ws[r][k4+0] = (__bf16)v.x; Ws[r][k4+1] = (__bf16)v.y;
            Ws[r][k4+2] = (__bf16)v.z; Ws[r][k4+3] = (__bf16)v.w;
        }
        __syncthreads();
        #pragma unroll
        for (int ks = 0; ks < 128; ks += 32) {
            bf16x8 a0 = *(const bf16x8*)&Xs[lr][ks + lk];
            bf16x8 b0 = *(const bf16x8*)&Ws[wn + lr][ks + lk];
            acc = MFMA(a0, b0, acc, 0, 0, 0);
        }
        __syncthreads();
    }
    #pragma unroll
    for (int q = 0; q < 4; ++q) {
        int gm = bm + (lane >> 4) * 4 + q;
        int b = gm / 196, f = gm % 196;
        int p = f + (f >= 98);
        int gn = bn + wn + (lane & 15);
        residual[((size_t)b * L + p) * DM + gn] =
            acc[q] + pb[gn] + pos[(size_t)p * DM + gn];
    }
}

__global__ __launch_bounds__(192)
void cls_pos_k(const float* __restrict__ cls, const float* __restrict__ pos,
               float* __restrict__ residual)
{
    int c = threadIdx.x;
    float v = cls[c] + pos[98 * DM + c];
    for (int b = 0; b < B; ++b)
        residual[((size_t)b * L + 98) * DM + c] = v;
}

// ---------------------------------------------------------------------------
// gemm1: xz16 = rmsnorm(residual)*nw @ w1bf^T   [1576,192]x[768,192]^T.
// BN=96 -> grid (8,25) = 200 blocks. Output written bf16. (R14-proven)
// ---------------------------------------------------------------------------
__global__ __launch_bounds__(256)
void gemm1_rms_k(const float* __restrict__ residual, const float* __restrict__ nw,
                 const __bf16* __restrict__ w1bf, __bf16* __restrict__ O)
{
    __shared__ __bf16 Xs[64][200];
    __shared__ __bf16 Ws[96][200];
    __shared__ float sinv[64];
    const int bm = blockIdx.y * 64;
    const int bn = blockIdx.x * 96;
    const int tid = threadIdx.x;
    const int lane = tid & 63, wv = tid >> 6;
    const int wm = (wv >> 1) * 32, wn = (wv & 1) * 48;
    const int lr = lane & 15, lk = (lane >> 4) * 8;
    {   // per-row inv rms: 4 threads/row
        int r = tid >> 2, q = tid & 3;
        int gm = bm + r;
        float s = 0.f;
        if (gm < MROWS) {
            const float4* xr = (const float4*)(residual + (size_t)gm * DM);
            #pragma unroll
            for (int i = 0; i < 12; ++i) {
                float4 v = xr[q + i * 4];
                s += v.x*v.x + v.y*v.y + v.z*v.z + v.w*v.w;
            }
        }
        s += __shfl_xor(s, 1, 4);
        s += __shfl_xor(s, 2, 4);
        if (q == 0) sinv[r] = rsqrtf(s * (1.f / DM) + 1e-5f);
    }
    __syncthreads();
    for (int i = tid; i < 64 * 48; i += 256) {
        int r = i / 48, k4 = (i % 48) * 4;
        int gm = bm + r;
        float4 v = {0.f, 0.f, 0.f, 0.f};
        if (gm < MROWS) v = *(const float4*)&residual[(size_t)gm * DM + k4];
        float sc = sinv[r];
        float4 w4 = *(const float4*)&nw[k4];
        Xs[r][k4+0] = (__bf16)(v.x * sc * w4.x);
        Xs[r][k4+1] = (__bf16)(v.y * sc * w4.y);
        Xs[r][k4+2] = (__bf16)(v.z * sc * w4.z);
        Xs[r][k4+3] = (__bf16)(v.w * sc * w4.w);
    }
    for (int i = tid; i < 96 * 24; i += 256) {
        int r = i / 24, c8 = (i % 24) * 8;
        *(bf16x8*)&Ws[r][c8] = *(const bf16x8*)&w1bf[(size_t)(bn + r) * DM + c8];
    }
    __syncthreads();
    f32x4 acc[2][3] = {};
    #pragma unroll
    for (int ks = 0; ks < 192; ks += 32) {
        bf16x8 a0 = *(const bf16x8*)&Xs[wm + lr][ks + lk];
        bf16x8 a1 = *(const bf16x8*)&Xs[wm + 16 + lr][ks + lk];
        #pragma unroll
        for (int n = 0; n < 3; ++n) {
            bf16x8 bb = *(const bf16x8*)&Ws[wn + n * 16 + lr][ks + lk];
            acc[0][n] = MFMA(a0, bb, acc[0][n], 0, 0, 0);
            acc[1][n] = MFMA(a1, bb, acc[1][n], 0, 0, 0);
        }
    }
    #pragma unroll
    for (int i = 0; i < 2; ++i)
        #pragma unroll
        for (int q = 0; q < 4; ++q) {
            int gm = bm + wm + i * 16 + (lane >> 4) * 4 + q;
            if (gm >= MROWS) continue;
            #pragma unroll
            for (int n = 0; n < 3; ++n) {
                int gn = bn + wn + n * 16 + (lane & 15);
                O[(size_t)gm * (2 * DI) + gn] = (__bf16)acc[i][n][q];
            }
        }
}

// ---------------------------------------------------------------------------
// Depthwise causal conv1d + bias + silu, x4 vectorized, bf16 in/out. grid 591.
// ---------------------------------------------------------------------------
__global__ __launch_bounds__(256)
void conv_silu_k(const __bf16* __restrict__ xz16, const float* __restrict__ cw,
                 const float* __restrict__ cb, __bf16* __restrict__ xcb16)
{
    int idx4 = (blockIdx.x * 256 + threadIdx.x) * 4;
    if (idx4 >= MROWS * DI) return;
    int d = idx4 % DI;
    int row = idx4 / DI;
    int t = row % L;
    float a0 = cb[d], a1 = cb[d+1], a2 = cb[d+2], a3 = cb[d+3];
    #pragma unroll
    for (int j = 0; j < 4; ++j) {
        if (t - 3 + j >= 0) {
            bf16x4 v = *(const bf16x4*)&xz16[(size_t)(row - 3 + j) * (2 * DI) + d];
            a0 += (float)v[0] * cw[(d+0) * 4 + j];
            a1 += (float)v[1] * cw[(d+1) * 4 + j];
            a2 += (float)v[2] * cw[(d+2) * 4 + j];
            a3 += (float)v[3] * cw[(d+3) * 4 + j];
        }
    }
    bf16x4 h;
    h[0] = (__bf16)siluf(a0); h[1] = (__bf16)siluf(a1);
    h[2] = (__bf16)siluf(a2); h[3] = (__bf16)siluf(a3);
    *(bf16x4*)&xcb16[idx4] = h;
}

// ---------------------------------------------------------------------------
// gemm2: xdb = xc_bf16 @ W_aug^T  [1576,384]x[416,384]^T, grid (7,25)=175.
// Softplus + dt bias epilogue on first 384 output channels.
// ---------------------------------------------------------------------------
__global__ __launch_bounds__(256)
void gemm2_k(const __bf16* __restrict__ xcb16, const __bf16* __restrict__ waug,
             const float* __restrict__ dtbias, float* __restrict__ xdb)
{
    __shared__ __bf16 Xs[64][136];
    __shared__ __bf16 Ws[64][136];
    const int bm = blockIdx.y * 64;
    const int bn = blockIdx.x * 64;
    const int tid = threadIdx.x;
    const int lane = tid & 63, wv = tid >> 6;
    const int wm = (wv >> 1) * 32, wn = (wv & 1) * 32;
    const int lr = lane & 15, lk = (lane >> 4) * 8;
    f32x4 acc[2][2] = {};
    for (int k0 = 0; k0 < DI; k0 += 128) {
        for (int i = tid; i < 64 * 16; i += 256) {
            int r = i >> 4, c8 = (i & 15) * 8;
            int gm = bm + r;
            bf16x8 v = {};
            if (gm < MROWS) v = *(const bf16x8*)&xcb16[(size_t)gm * DI + k0 + c8];
            *(bf16x8*)&Xs[r][c8] = v;
        }
        for (int i = tid; i < 64 * 16; i += 256) {
            int r = i >> 4, c8 = (i & 15) * 8;
            int gn = bn + r;
            bf16x8 v = {};
            if (gn < XDN) v = *(const bf16x8*)&waug[(size_t)gn * DI + k0 + c8];
            *(bf16x8*)&Ws[r][c8] = v;
        }
        __syncthreads();
        #pragma unroll
        for (int ks = 0; ks < 128; ks += 32) {
            bf16x8 a0 = *(const bf16x8*)&Xs[wm + lr][ks + lk];
            bf16x8 a1 = *(const bf16x8*)&Xs[wm + 16 + lr][ks + lk];
            bf16x8 b0 = *(const bf16x8*)&Ws[wn + lr][ks + lk];
            bf16x8 b1 = *(const bf16x8*)&Ws[wn + 16 + lr][ks + lk];
            acc[0][0] = MFMA(a0, b0, acc[0][0], 0, 0, 0);
            acc[0][1] = MFMA(a0, b1, acc[0][1], 0, 0, 0);
            acc[1][0] = MFMA(a1, b0, acc[1][0], 0, 0, 0);
            acc[1][1] = MFMA(a1, b1, acc[1][1], 0, 0, 0);
        }
        __syncthreads();
    }
    #pragma unroll
    for (int i = 0; i < 2; ++i)
        #pragma unroll
        for (int q = 0; q < 4; ++q) {
            int gm = bm + wm + i * 16 + (lane >> 4) * 4 + q;
            if (gm >= MROWS) continue;
            #pragma unroll
            for (int j = 0; j < 2; ++j) {
                int gn = bn + wn + j * 16 + (lane & 15);
                if (gn >= XDN) continue;
                float v = acc[i][j][q];
                if (gn < 384) {
                    v += dtbias[gn];
                    v = (v > 20.f) ? v : __logf(1.f + __expf(v));
                }
                xdb[(size_t)gm * XDN + gn] = v;
            }
        }
}

// ---------------------------------------------------------------------------
// Selective scan. Staging: dt/B/C coalesced fp32 from xdb; u from bf16 xcb16;
// z (gate) from bf16 xz16. DPP reduce + fast exp. Output bf16. grid 192.
// ---------------------------------------------------------------------------
__global__ __launch_bounds__(256)
void scan_fused_k(const float* __restrict__ xdb, const __bf16* __restrict__ xcb16,
                  const __bf16* __restrict__ xz16, const float* __restrict__ Alog,
                  const float* __restrict__ Dp, __bf16* __restrict__ yg16)
{
    __shared__ float sdt[L * 16];
    __shared__ float su [L * 16];
    __shared__ float sB [L * 16];
    __shared__ float sC [L * 16];
    __shared__ float sy [L * 16];

    const int blk = blockIdx.x;
    const int b = blk / (DI / 16);
    const int dc = blk % (DI / 16);
    const int tid = threadIdx.x;

    for (int idx = tid; idx < L * 16; idx += 256) {
        int t = idx >> 4, c = idx & 15;
        size_t row = (size_t)(b * L + t);
        const float* xr = xdb + row * XDN;
        sdt[idx] = xr[dc * 16 + c];
        sB[idx]  = xr[384 + c];
        sC[idx]  = xr[400 + c];
        su[idx]  = (float)xcb16[row * DI + dc * 16 + c];
    }
    __syncthreads();

    const int nl = tid & 15;
    const int dl = tid >> 4;
    const int d = dc * 16 + dl;
    const float Acoef = -__expf(Alog[d * NS + nl]);
    const float Dv = Dp[d];
    float h = 0.f;
    #pragma unroll 8
    for (int t = 0; t < L; ++t) {
        float dtv = sdt[t * 16 + dl];
        float u   = su [t * 16 + dl];
        float Bv  = sB [t * 16 + nl];
        float Cv  = sC [t * 16 + nl];
        float dA = __expf(dtv * Acoef);
        h = dA * h + (dtv * u) * Bv;
        float p = row_sum16(h * Cv);
        if (nl == 0) sy[t * 16 + dl] = p + u * Dv;
    }
    __syncthreads();

    for (int idx = tid; idx < L * 16; idx += 256) {
        int t = idx >> 4, c = idx & 15;
        size_t row = (size_t)(b * L + t);
        float z = (float)xz16[row * (2 * DI) + DI + dc * 16 + c];
        yg16[row * DI + dc * 16 + c] = (__bf16)(sy[idx] * siluf(z));
    }
}

// ---------------------------------------------------------------------------
// gemm3: residual += yg16 @ w3bf^T  [1576,384]x[192,384]^T. grid (3, 25).
// Both operands staged from bf16.
// ---------------------------------------------------------------------------
__global__ __launch_bounds__(256)
void gemm3_resid_k(const __bf16* __restrict__ yg16, const __bf16* __restrict__ w3bf,
                   float* __restrict__ residual)
{
    __shared__ __bf16 Xs[64][136];
    __shared__ __bf16 Ws[64][136];
    const int bm = blockIdx.y * 64;
    const int bn = blockIdx.x * 64;
    const int tid = threadIdx.x;
    const int lane = tid & 63, wv = tid >> 6;
    const int wm = (wv >> 1) * 32, wn = (wv & 1) * 32;
    const int lr = lane & 15, lk = (lane >> 4) * 8;
    f32x4 acc[2][2] = {};
    for (int k0 = 0; k0 < DI; k0 += 128) {
        for (int i = tid; i < 64 * 16; i += 256) {
            int r = i >> 4, c8 = (i & 15) * 8;
            int gm = bm + r;
            bf16x8 v = {};
            if (gm < MROWS) v = *(const bf16x8*)&yg16[(size_t)gm * DI + k0 + c8];
            *(bf16x8*)&Xs[r][c8] = v;
        }
        for (int i = tid; i < 64 * 16; i += 256) {
            int r = i >> 4, c8 = (i & 15) * 8;
            *(bf16x8*)&Ws[r][c8] = *(const bf16x8*)&w3bf[(size_t)(bn + r) * DI + k0 + c8];
        }
        __syncthreads();
        #pragma unroll
        for (int ks = 0; ks < 128; ks += 32) {
            bf16x8 a0 = *(const bf16x8*)&Xs[wm + lr][ks + lk];
            bf16x8 a1 = *(const bf16x8*)&Xs[wm + 16 + lr][ks + lk];
            bf16x8 b0 = *(const bf16x8*)&Ws[wn + lr][ks + lk];
            bf16x8 b1 = *(const bf16x8*)&Ws[wn + 16 + lr][ks + lk];
            acc[0][0] = MFMA(a0, b0, acc[0][0], 0, 0, 0);
            acc[0][1] = MFMA(a0, b1, acc[0][1], 0, 0, 0);
            acc[1][0] = MFMA(a1, b0, acc[1][0], 0, 0, 0);
            acc[1][1] = MFMA(a1, b1, acc[1][1], 0, 0, 0);
        }
        __syncthreads();
    }
    #pragma unroll
    for (int i = 0; i < 2; ++i)
        #pragma unroll
        for (int q = 0; q < 4; ++q) {
            int gm = bm + wm + i * 16 + (lane >> 4) * 4 + q;
            if (gm >= MROWS) continue;
            #pragma unroll
            for (int j = 0; j < 2; ++j) {
                int gn = bn + wn + j * 16 + (lane & 15);
                size_t off = (size_t)gm * DM + gn;
                residual[off] += acc[i][j][q];
            }
        }
}

// ---------------------------------------------------------------------------
// Final: rmsnorm(residual) at cls row then head GEMV. One block/batch.
// ---------------------------------------------------------------------------
__global__ __launch_bounds__(256)
void final_head_k(const float* __restrict__ residual, const float* __restrict__ nfw,
                  const float* __restrict__ hw, const float* __restrict__ hb,
                  float* __restrict__ out)
{
    int b = blockIdx.x;
    int tid = threadIdx.x;
    __shared__ float rowv[DM];
    __shared__ float wsum[4];
    size_t off = ((size_t)b * L + 98) * DM;
    float v = 0.f;
    if (tid < DM) v = residual[off + tid];
    float s = v * v;
    #pragma unroll
    for (int o = 32; o; o >>= 1) s += __shfl_down(s, o);
    if ((tid & 63) == 0) wsum[tid >> 6] = s;
    __syncthreads();
    float total = wsum[0] + wsum[1] + wsum[2] + wsum[3];
    float rs = rsqrtf(total * (1.f / DM) + 1e-5f);
    if (tid < DM) rowv[tid] = v * rs * nfw[tid];
    __syncthreads();
    for (int o = tid; o < 1000; o += 256) {
        float acc = hb[o];
        const float* w = hw + (size_t)o * DM;
        #pragma unroll 8
        for (int k = 0; k < DM; ++k) acc += w[k] * rowv[k];
        out[(size_t)b * 1000 + o] = acc;
    }
}

// ---------------------------------------------------------------------------
extern "C" void kernel_launch(void* const* d_in, const int* in_sizes, int n_in,
                              void* d_out, int out_size, void* d_ws, size_t ws_size,
                              hipStream_t stream)
{
    const float* x        = (const float*)d_in[0];
    const float* patch_w  = (const float*)d_in[1];
    const float* patch_b  = (const float*)d_in[2];
    const float* cls_tok  = (const float*)d_in[3];
    const float* pos_emb  = (const float*)d_in[4];
    const float* norm_w   = (const float*)d_in[5];
    const float* in_w     = (const float*)d_in[6];
    const float* conv_w   = (const float*)d_in[7];
    const float* conv_b   = (const float*)d_in[8];
    const float* xproj_w  = (const float*)d_in[9];
    const float* dt_w     = (const float*)d_in[10];
    const float* dt_b     = (const float*)d_in[11];
    const float* A_log    = (const float*)d_in[12];
    const float* D_par    = (const float*)d_in[13];
    const float* out_w    = (const float*)d_in[14];
    const float* norm_fw  = (const float*)d_in[15];
    const float* head_w   = (const float*)d_in[16];
    const float* head_b   = (const float*)d_in[17];

    float* ws = (float*)d_ws;
    float* residual = ws;  ws += (size_t)MROWS * DM;
    float* xdb      = ws;  ws += (size_t)MROWS * XDN;
    __bf16* xzb16   = (__bf16*)ws;  ws += (size_t)MROWS * 2 * DI / 2;
    __bf16* xcb16   = (__bf16*)ws;  ws += (size_t)MROWS * DI / 2;
    __bf16* yg16    = (__bf16*)ws;  ws += (size_t)MROWS * DI / 2;
    __bf16* waug    = (__bf16*)ws;  ws += (size_t)DEPTH_ * XDN * DI / 2;
    __bf16* w1bf    = (__bf16*)ws;  ws += (size_t)DEPTH_ * 2 * DI * DM / 2;
    __bf16* w3bf    = (__bf16*)ws;  ws += (size_t)DEPTH_ * DM * DI / 2;

    const int n1 = DEPTH_ * 2 * DI * DM;
    const int n3 = DEPTH_ * DM * DI;
    waug_k<<<dim3(XDN, DEPTH_), 384, 0, stream>>>(xproj_w, dt_w, waug);
    f2bf_k<<<(n1 + 255) / 256, 256, 0, stream>>>(in_w, w1bf, n1);
    f2bf_k<<<(n3 + 255) / 256, 256, 0, stream>>>(out_w, w3bf, n3);
    patch_gemm_k<<<dim3(3, 98), 256, 0, stream>>>(x, patch_w, patch_b, pos_emb, residual);
    cls_pos_k<<<1, DM, 0, stream>>>(cls_tok, pos_emb, residual);

    for (int l = 0; l < DEPTH_; ++l) {
        gemm1_rms_k<<<dim3(8, 25), 256, 0, stream>>>(residual, norm_w + l * DM,
                                                     w1bf + (size_t)l * 2 * DI * DM, xzb16);
        conv_silu_k<<<591, 256, 0, stream>>>(xzb16, conv_w + l * DI * 4, conv_b + l * DI,
                                             xcb16);
        gemm2_k<<<dim3(7, 25), 256, 0, stream>>>(xcb16, waug + (size_t)l * XDN * DI,
                                                 dt_b + l * DI, xdb);
        scan_fused_k<<<B * (DI / 16), 256, 0, stream>>>(xdb, xcb16, xzb16,
                                                        A_log + (size_t)l * DI * NS,
                                                        D_par + l * DI, yg16);
        gemm3_resid_k<<<dim3(3, 25), 256, 0, stream>>>(yg16, w3bf + (size_t)l * DM * DI,
                                                       residual);
    }
    final_head_k<<<B, 256, 0, stream>>>(residual, norm_fw, head_w, head_b, (float*)d_out);
}